// Round 11
// baseline (449.228 us; speedup 1.0000x reference)
//
#include <hip/hip_runtime.h>
#include <math.h>

#define B_ 4
#define T_ 2048
#define C_ 1024
#define H_ 16
#define D_ 64
// M=8192, K=1024, N1=3072, N2=1024

typedef __attribute__((ext_vector_type(8))) short bf16x8;
typedef __attribute__((ext_vector_type(4))) float f32x4;

__device__ inline ushort f2bf(float f) {
    union { float f; unsigned u; } v; v.f = f;
    unsigned u = v.u;
    return (ushort)((u + 0x7FFFu + ((u >> 16) & 1u)) >> 16);
}

// --------------------------- x fp32 -> bf16 --------------------------------
__global__ __launch_bounds__(256) void convert_x(
    const float* __restrict__ in, ushort* __restrict__ out, int n8)
{
    int i = blockIdx.x * 256 + threadIdx.x;
    if (i >= n8) return;
    float4 a = *reinterpret_cast<const float4*>(&in[i * 8]);
    float4 b = *reinterpret_cast<const float4*>(&in[i * 8 + 4]);
    ushort o[8] = { f2bf(a.x), f2bf(a.y), f2bf(a.z), f2bf(a.w),
                    f2bf(b.x), f2bf(b.y), f2bf(b.z), f2bf(b.w) };
    *reinterpret_cast<bf16x8*>(&out[i * 8]) = *reinterpret_cast<bf16x8*>(o);
}

// ------------------ W fp32 [K,N] -> bf16 W^T [N,K] -------------------------
__global__ __launch_bounds__(256) void transpose_w(
    const float* __restrict__ in, ushort* __restrict__ out, int K, int N)
{
    __shared__ float tile[32][33];
    int k0 = blockIdx.y * 32, n0 = blockIdx.x * 32;
    int tr = threadIdx.x >> 3, tc = (threadIdx.x & 7) * 4;
    float4 v = *reinterpret_cast<const float4*>(&in[(size_t)(k0 + tr) * N + n0 + tc]);
    tile[tr][tc + 0] = v.x; tile[tr][tc + 1] = v.y;
    tile[tr][tc + 2] = v.z; tile[tr][tc + 3] = v.w;
    __syncthreads();
    ushort o[4];
#pragma unroll
    for (int i = 0; i < 4; ++i) o[i] = f2bf(tile[tc + i][tr]);
    *reinterpret_cast<ushort2*>(&out[(size_t)(n0 + tr) * K + k0 + tc]) =
        *reinterpret_cast<ushort2*>(&o[0]);
    *reinterpret_cast<ushort2*>(&out[(size_t)(n0 + tr) * K + k0 + tc + 2]) =
        *reinterpret_cast<ushort2*>(&o[2]);
}

// ---------------- bf16 MFMA GEMM: C = A[M,K] * Bt[N,K]^T -------------------
// 128x128 tile, BK=32, 4 waves (2x2 of 64x64), 16x16x32 MFMA.
#define APAD 40
__device__ inline void gemm_core(
    const ushort* __restrict__ Abase, const ushort* __restrict__ Bt,
    int K, int bm, int bn, ushort (*As)[APAD], ushort (*Bs)[APAD],
    f32x4 acc[4][4], int a_is_headlayout)
{
    const int tid = threadIdx.x;
    const int wid = tid >> 6, lane = tid & 63;
    const int lr = lane & 15, lg = lane >> 4;
    const int wr = wid >> 1, wc = wid & 1;

    for (int k0 = 0; k0 < K; k0 += 32) {
        __syncthreads();
#pragma unroll
        for (int i = 0; i < 2; ++i) {
            int f = tid + 256 * i;
            int r = f >> 2, c = (f & 3) * 8;
            const ushort* src;
            if (a_is_headlayout) {
                int m = bm + r, b = m >> 11, t = m & (T_ - 1);
                int kk = k0 + c, h = kk >> 6, d = kk & 63;
                src = &Abase[((((size_t)b * H_ + h) * T_) + t) * D_ + d];
            } else {
                src = &Abase[(size_t)(bm + r) * K + k0 + c];
            }
            *reinterpret_cast<bf16x8*>(&As[r][c]) =
                *reinterpret_cast<const bf16x8*>(src);
        }
#pragma unroll
        for (int i = 0; i < 2; ++i) {
            int f = tid + 256 * i;
            int r = f >> 2, c = (f & 3) * 8;
            *reinterpret_cast<bf16x8*>(&Bs[r][c]) =
                *reinterpret_cast<const bf16x8*>(&Bt[(size_t)(bn + r) * K + k0 + c]);
        }
        __syncthreads();

        bf16x8 a[4], b[4];
#pragma unroll
        for (int i = 0; i < 4; ++i) {
            a[i] = *reinterpret_cast<const bf16x8*>(&As[wr * 64 + i * 16 + lr][lg * 8]);
            b[i] = *reinterpret_cast<const bf16x8*>(&Bs[wc * 64 + i * 16 + lr][lg * 8]);
        }
#pragma unroll
        for (int i = 0; i < 4; ++i)
#pragma unroll
            for (int j = 0; j < 4; ++j)
                acc[i][j] = __builtin_amdgcn_mfma_f32_16x16x32_bf16(a[i], b[j], acc[i][j], 0, 0, 0);
    }
}

__global__ __launch_bounds__(256) void gemm1_mfma(
    const ushort* __restrict__ A,   // x bf16 [8192,1024]
    const ushort* __restrict__ Bt,  // w_qkv^T bf16 [3072,1024]
    const float* __restrict__ bias,
    ushort* __restrict__ qo, ushort* __restrict__ ko, ushort* __restrict__ vo)
{
    __shared__ ushort As[128][APAD];
    __shared__ ushort Bs[128][APAD];
    const int bm = blockIdx.y * 128, bn = blockIdx.x * 128;
    const int lane = threadIdx.x & 63, wid = threadIdx.x >> 6;
    const int lr = lane & 15, lg = lane >> 4;
    const int wr = wid >> 1, wc = wid & 1;
    f32x4 acc[4][4];
#pragma unroll
    for (int i = 0; i < 4; ++i)
#pragma unroll
        for (int j = 0; j < 4; ++j) acc[i][j] = (f32x4)(0.f);

    gemm_core(A, Bt, C_, bm, bn, As, Bs, acc, 0);

#pragma unroll
    for (int i = 0; i < 4; ++i)
#pragma unroll
        for (int r = 0; r < 4; ++r) {
            int m = bm + wr * 64 + i * 16 + lg * 4 + r;
            int b = m >> 11, t = m & (T_ - 1);
#pragma unroll
            for (int j = 0; j < 4; ++j) {
                int n = bn + wc * 64 + j * 16 + lr;
                float val = acc[i][j][r] + bias[n];
                int sel = n >> 10, rem = n & 1023;
                int h = rem >> 6, d = rem & 63;
                size_t bh = (size_t)b * H_ + h;
                if (sel == 0)      qo[(bh * T_ + t) * D_ + d] = f2bf(val * 0.125f);
                else if (sel == 1) ko[(bh * T_ + t) * D_ + d] = f2bf(val);
                else               vo[(bh * D_ + d) * T_ + t] = f2bf(val);
            }
        }
}

__global__ __launch_bounds__(256) void gemm2_mfma(
    const ushort* __restrict__ A,   // attn out bf16 [B*H,T,D] head layout
    const ushort* __restrict__ Bt,  // w_out^T bf16 [1024,1024]
    const float* __restrict__ bias,
    float* __restrict__ out)        // [8192,1024] fp32
{
    __shared__ ushort As[128][APAD];
    __shared__ ushort Bs[128][APAD];
    const int bm = blockIdx.y * 128, bn = blockIdx.x * 128;
    const int lane = threadIdx.x & 63, wid = threadIdx.x >> 6;
    const int lr = lane & 15, lg = lane >> 4;
    const int wr = wid >> 1, wc = wid & 1;
    f32x4 acc[4][4];
#pragma unroll
    for (int i = 0; i < 4; ++i)
#pragma unroll
        for (int j = 0; j < 4; ++j) acc[i][j] = (f32x4)(0.f);

    gemm_core(A, Bt, C_, bm, bn, As, Bs, acc, 1);

#pragma unroll
    for (int i = 0; i < 4; ++i)
#pragma unroll
        for (int r = 0; r < 4; ++r) {
            int m = bm + wr * 64 + i * 16 + lg * 4 + r;
#pragma unroll
            for (int j = 0; j < 4; ++j) {
                int n = bn + wc * 64 + j * 16 + lr;
                out[(size_t)m * C_ + n] = acc[i][j][r] + bias[n];
            }
        }
}

// ------------------------- flash attention ---------------------------------
// One q-tile per block; LONGEST-FIRST dispatch (qt = 31 - x) so the grid tail
// consists of the shortest blocks. 2048 blocks -> up to 6 resident/CU (LDS).
#define KPAD 72
#define PPAD 68
#define NT_ (T_ / 64)   // 32 q-tiles
__global__ __launch_bounds__(256) void attn_mfma(
    const ushort* __restrict__ q, const ushort* __restrict__ k,
    const ushort* __restrict__ vt, ushort* __restrict__ o)  // bf16 out
{
    __shared__ ushort Ks[64][KPAD];
    __shared__ ushort Vs[64][KPAD];
    __shared__ ushort Ps[4][16][PPAD];
    const int tid = threadIdx.x;
    const int wid = tid >> 6, lane = tid & 63;
    const int bh = blockIdx.y;
    const int qt = NT_ - 1 - (int)blockIdx.x;   // longest-first
    const int q0 = qt * 64;
    const int qw = q0 + wid * 16;
    const int lr = lane & 15, lg = lane >> 4;
    const ushort* qb = q + (size_t)bh * T_ * D_;
    const ushort* kb = k + (size_t)bh * T_ * D_;
    const ushort* vb = vt + (size_t)bh * D_ * T_;

    bf16x8 qf[2];
    qf[0] = *reinterpret_cast<const bf16x8*>(&qb[(size_t)(qw + lr) * D_ + lg * 8]);
    qf[1] = *reinterpret_cast<const bf16x8*>(&qb[(size_t)(qw + lr) * D_ + 32 + lg * 8]);

    f32x4 acc[4];
#pragma unroll
    for (int i = 0; i < 4; ++i) acc[i] = (f32x4)(0.f);
    float m[4], l[4];
#pragma unroll
    for (int r = 0; r < 4; ++r) { m[r] = -INFINITY; l[r] = 0.f; }

    const int ntiles = qt + 1;
    for (int t = 0; t < ntiles; ++t) {
        const int kv0 = t * 64;
        __syncthreads();
#pragma unroll
        for (int i = 0; i < 2; ++i) {
            int c = tid + 256 * i;
            int row = c >> 3, col = (c & 7) * 8;
            *reinterpret_cast<bf16x8*>(&Ks[row][col]) =
                *reinterpret_cast<const bf16x8*>(&kb[(size_t)(kv0 + row) * D_ + col]);
        }
#pragma unroll
        for (int i = 0; i < 2; ++i) {
            int c = tid + 256 * i;
            int d = c >> 3, col = (c & 7) * 8;
            *reinterpret_cast<bf16x8*>(&Vs[d][col]) =
                *reinterpret_cast<const bf16x8*>(&vb[(size_t)d * T_ + kv0 + col]);
        }
        __syncthreads();

        f32x4 sv[4];
#pragma unroll
        for (int sub = 0; sub < 4; ++sub) {
            f32x4 c = (f32x4)(0.f);
            bf16x8 b0 = *reinterpret_cast<const bf16x8*>(&Ks[sub * 16 + lr][lg * 8]);
            bf16x8 b1 = *reinterpret_cast<const bf16x8*>(&Ks[sub * 16 + lr][32 + lg * 8]);
            c = __builtin_amdgcn_mfma_f32_16x16x32_bf16(qf[0], b0, c, 0, 0, 0);
            c = __builtin_amdgcn_mfma_f32_16x16x32_bf16(qf[1], b1, c, 0, 0, 0);
            sv[sub] = c;
        }
        if (t == ntiles - 1) {
#pragma unroll
            for (int sub = 0; sub < 4; ++sub)
#pragma unroll
                for (int r = 0; r < 4; ++r)
                    if (sub * 16 + lr > wid * 16 + lg * 4 + r) sv[sub][r] = -INFINITY;
        }
        float rescale[4];
#pragma unroll
        for (int r = 0; r < 4; ++r) {
            float v0 = fmaxf(fmaxf(sv[0][r], sv[1][r]), fmaxf(sv[2][r], sv[3][r]));
            v0 = fmaxf(v0, __shfl_xor(v0, 1));
            v0 = fmaxf(v0, __shfl_xor(v0, 2));
            v0 = fmaxf(v0, __shfl_xor(v0, 4));
            v0 = fmaxf(v0, __shfl_xor(v0, 8));
            float mn = fmaxf(m[r], v0);
            rescale[r] = __expf(m[r] - mn);
            m[r] = mn;
            l[r] *= rescale[r];
        }
#pragma unroll
        for (int ds = 0; ds < 4; ++ds)
#pragma unroll
            for (int r = 0; r < 4; ++r) acc[ds][r] *= rescale[r];
#pragma unroll
        for (int sub = 0; sub < 4; ++sub)
#pragma unroll
            for (int r = 0; r < 4; ++r)
                sv[sub][r] = __expf(sv[sub][r] - m[r]);
#pragma unroll
        for (int r = 0; r < 4; ++r) {
            float s = sv[0][r] + sv[1][r] + sv[2][r] + sv[3][r];
            s += __shfl_xor(s, 1);
            s += __shfl_xor(s, 2);
            s += __shfl_xor(s, 4);
            s += __shfl_xor(s, 8);
            l[r] += s;
        }
#pragma unroll
        for (int sub = 0; sub < 4; ++sub)
#pragma unroll
            for (int r = 0; r < 4; ++r)
                Ps[wid][lg * 4 + r][sub * 16 + lr] = f2bf(sv[sub][r]);
#pragma unroll
        for (int kc = 0; kc < 2; ++kc) {
            bf16x8 pa = *reinterpret_cast<const bf16x8*>(&Ps[wid][lr][kc * 32 + lg * 8]);
#pragma unroll
            for (int ds = 0; ds < 4; ++ds) {
                bf16x8 vv = *reinterpret_cast<const bf16x8*>(&Vs[ds * 16 + lr][kc * 32 + lg * 8]);
                acc[ds] = __builtin_amdgcn_mfma_f32_16x16x32_bf16(pa, vv, acc[ds], 0, 0, 0);
            }
        }
    }
    ushort* ob = o + (size_t)bh * T_ * D_;
#pragma unroll
    for (int r = 0; r < 4; ++r) {
        float inv = 1.f / l[r];
        int row = qw + lg * 4 + r;
#pragma unroll
        for (int ds = 0; ds < 4; ++ds)
            ob[(size_t)row * D_ + ds * 16 + lr] = f2bf(acc[ds][r] * inv);
    }
}

// ---------------------------------------------------------------------------
extern "C" void kernel_launch(void* const* d_in, const int* in_sizes, int n_in,
                              void* d_out, int out_size, void* d_ws, size_t ws_size,
                              hipStream_t stream) {
    const float* x     = (const float*)d_in[0];
    const float* w_qkv = (const float*)d_in[1];
    const float* b_qkv = (const float*)d_in[2];
    const float* w_out = (const float*)d_in[3];
    const float* b_out = (const float*)d_in[4];
    float* out = (float*)d_out;

    const size_t per = (size_t)B_ * H_ * T_ * D_;  // 8M
    ushort* qws   = (ushort*)d_ws;          // 16MB
    ushort* kws   = qws + per;              // 16MB
    ushort* vtws  = kws + per;              // 16MB
    ushort* ows   = vtws + per;             // attn out bf16, 16MB
    ushort* xbf   = ows + per;              // x bf16, 16MB
    ushort* wqkvT = xbf + per;              // 3072*1024 bf16, 6MB
    ushort* woutT = wqkvT + (size_t)3 * C_ * C_; // 1024*1024 bf16, 2MB

    convert_x<<<(B_ * T_ * C_ / 8 + 255) / 256, 256, 0, stream>>>(x, xbf, B_ * T_ * C_ / 8);
    transpose_w<<<dim3(3 * C_ / 32, C_ / 32), 256, 0, stream>>>(w_qkv, wqkvT, C_, 3 * C_);
    transpose_w<<<dim3(C_ / 32, C_ / 32), 256, 0, stream>>>(w_out, woutT, C_, C_);

    dim3 g1(3 * C_ / 128, (B_ * T_) / 128);
    gemm1_mfma<<<g1, 256, 0, stream>>>(xbf, wqkvT, b_qkv, qws, kws, vtws);

    dim3 ga(NT_, B_ * H_);  // (32, 64): one q-tile/block, longest-first
    attn_mfma<<<ga, 256, 0, stream>>>(qws, kws, vtws, ows);

    dim3 g2(C_ / 128, (B_ * T_) / 128);
    gemm2_mfma<<<g2, 256, 0, stream>>>(ows, woutT, b_out, out);
}

// Round 12
// 335.234 us; speedup vs baseline: 1.3400x; 1.3400x over previous
//
#include <hip/hip_runtime.h>
#include <math.h>

#define B_ 4
#define T_ 2048
#define C_ 1024
#define H_ 16
#define D_ 64
// M=8192, K=1024, N1=3072, N2=1024

typedef __attribute__((ext_vector_type(8))) short bf16x8;
typedef __attribute__((ext_vector_type(4))) float f32x4;

__device__ inline ushort f2bf(float f) {
    union { float f; unsigned u; } v; v.f = f;
    unsigned u = v.u;
    return (ushort)((u + 0x7FFFu + ((u >> 16) & 1u)) >> 16);
}

// --------------------------- x fp32 -> bf16 --------------------------------
__global__ __launch_bounds__(256) void convert_x(
    const float* __restrict__ in, ushort* __restrict__ out, int n8)
{
    int i = blockIdx.x * 256 + threadIdx.x;
    if (i >= n8) return;
    float4 a = *reinterpret_cast<const float4*>(&in[i * 8]);
    float4 b = *reinterpret_cast<const float4*>(&in[i * 8 + 4]);
    ushort o[8] = { f2bf(a.x), f2bf(a.y), f2bf(a.z), f2bf(a.w),
                    f2bf(b.x), f2bf(b.y), f2bf(b.z), f2bf(b.w) };
    *reinterpret_cast<bf16x8*>(&out[i * 8]) = *reinterpret_cast<bf16x8*>(o);
}

// ------------------ W fp32 [K,N] -> bf16 W^T [N,K] -------------------------
__global__ __launch_bounds__(256) void transpose_w(
    const float* __restrict__ in, ushort* __restrict__ out, int K, int N)
{
    __shared__ float tile[32][33];
    int k0 = blockIdx.y * 32, n0 = blockIdx.x * 32;
    int tr = threadIdx.x >> 3, tc = (threadIdx.x & 7) * 4;
    float4 v = *reinterpret_cast<const float4*>(&in[(size_t)(k0 + tr) * N + n0 + tc]);
    tile[tr][tc + 0] = v.x; tile[tr][tc + 1] = v.y;
    tile[tr][tc + 2] = v.z; tile[tr][tc + 3] = v.w;
    __syncthreads();
    ushort o[4];
#pragma unroll
    for (int i = 0; i < 4; ++i) o[i] = f2bf(tile[tc + i][tr]);
    *reinterpret_cast<ushort2*>(&out[(size_t)(n0 + tr) * K + k0 + tc]) =
        *reinterpret_cast<ushort2*>(&o[0]);
    *reinterpret_cast<ushort2*>(&out[(size_t)(n0 + tr) * K + k0 + tc + 2]) =
        *reinterpret_cast<ushort2*>(&o[2]);
}

// ---------------- bf16 MFMA GEMM: C = A[M,K] * Bt[N,K]^T -------------------
// 128x128 tile, BK=32, 4 waves (2x2 of 64x64), 16x16x32 MFMA.
#define APAD 40
__device__ inline void gemm_core(
    const ushort* __restrict__ Abase, const ushort* __restrict__ Bt,
    int K, int bm, int bn, ushort (*As)[APAD], ushort (*Bs)[APAD],
    f32x4 acc[4][4], int a_is_headlayout)
{
    const int tid = threadIdx.x;
    const int wid = tid >> 6, lane = tid & 63;
    const int lr = lane & 15, lg = lane >> 4;
    const int wr = wid >> 1, wc = wid & 1;

    for (int k0 = 0; k0 < K; k0 += 32) {
        __syncthreads();
#pragma unroll
        for (int i = 0; i < 2; ++i) {
            int f = tid + 256 * i;
            int r = f >> 2, c = (f & 3) * 8;
            const ushort* src;
            if (a_is_headlayout) {
                int m = bm + r, b = m >> 11, t = m & (T_ - 1);
                int kk = k0 + c, h = kk >> 6, d = kk & 63;
                src = &Abase[((((size_t)b * H_ + h) * T_) + t) * D_ + d];
            } else {
                src = &Abase[(size_t)(bm + r) * K + k0 + c];
            }
            *reinterpret_cast<bf16x8*>(&As[r][c]) =
                *reinterpret_cast<const bf16x8*>(src);
        }
#pragma unroll
        for (int i = 0; i < 2; ++i) {
            int f = tid + 256 * i;
            int r = f >> 2, c = (f & 3) * 8;
            *reinterpret_cast<bf16x8*>(&Bs[r][c]) =
                *reinterpret_cast<const bf16x8*>(&Bt[(size_t)(bn + r) * K + k0 + c]);
        }
        __syncthreads();

        bf16x8 a[4], b[4];
#pragma unroll
        for (int i = 0; i < 4; ++i) {
            a[i] = *reinterpret_cast<const bf16x8*>(&As[wr * 64 + i * 16 + lr][lg * 8]);
            b[i] = *reinterpret_cast<const bf16x8*>(&Bs[wc * 64 + i * 16 + lr][lg * 8]);
        }
#pragma unroll
        for (int i = 0; i < 4; ++i)
#pragma unroll
            for (int j = 0; j < 4; ++j)
                acc[i][j] = __builtin_amdgcn_mfma_f32_16x16x32_bf16(a[i], b[j], acc[i][j], 0, 0, 0);
    }
}

__global__ __launch_bounds__(256) void gemm1_mfma(
    const ushort* __restrict__ A,   // x bf16 [8192,1024]
    const ushort* __restrict__ Bt,  // w_qkv^T bf16 [3072,1024]
    const float* __restrict__ bias,
    ushort* __restrict__ qo, ushort* __restrict__ ko, ushort* __restrict__ vo)
{
    __shared__ ushort As[128][APAD];
    __shared__ ushort Bs[128][APAD];
    const int bm = blockIdx.y * 128, bn = blockIdx.x * 128;
    const int lane = threadIdx.x & 63, wid = threadIdx.x >> 6;
    const int lr = lane & 15, lg = lane >> 4;
    const int wr = wid >> 1, wc = wid & 1;
    f32x4 acc[4][4];
#pragma unroll
    for (int i = 0; i < 4; ++i)
#pragma unroll
        for (int j = 0; j < 4; ++j) acc[i][j] = (f32x4)(0.f);

    gemm_core(A, Bt, C_, bm, bn, As, Bs, acc, 0);

    // q pre-scale folds 1/sqrt(D)=0.125 AND log2(e) so attention can use exp2.
    const float QSCALE = 0.125f * 1.4426950408889634f;
#pragma unroll
    for (int i = 0; i < 4; ++i)
#pragma unroll
        for (int r = 0; r < 4; ++r) {
            int m = bm + wr * 64 + i * 16 + lg * 4 + r;
            int b = m >> 11, t = m & (T_ - 1);
#pragma unroll
            for (int j = 0; j < 4; ++j) {
                int n = bn + wc * 64 + j * 16 + lr;
                float val = acc[i][j][r] + bias[n];
                int sel = n >> 10, rem = n & 1023;
                int h = rem >> 6, d = rem & 63;
                size_t bh = (size_t)b * H_ + h;
                if (sel == 0)      qo[(bh * T_ + t) * D_ + d] = f2bf(val * QSCALE);
                else if (sel == 1) ko[(bh * T_ + t) * D_ + d] = f2bf(val);
                else               vo[(bh * D_ + d) * T_ + t] = f2bf(val);
            }
        }
}

__global__ __launch_bounds__(256) void gemm2_mfma(
    const ushort* __restrict__ A,   // attn out bf16 [B*H,T,D] head layout
    const ushort* __restrict__ Bt,  // w_out^T bf16 [1024,1024]
    const float* __restrict__ bias,
    float* __restrict__ out)        // [8192,1024] fp32
{
    __shared__ ushort As[128][APAD];
    __shared__ ushort Bs[128][APAD];
    const int bm = blockIdx.y * 128, bn = blockIdx.x * 128;
    const int lane = threadIdx.x & 63, wid = threadIdx.x >> 6;
    const int lr = lane & 15, lg = lane >> 4;
    const int wr = wid >> 1, wc = wid & 1;
    f32x4 acc[4][4];
#pragma unroll
    for (int i = 0; i < 4; ++i)
#pragma unroll
        for (int j = 0; j < 4; ++j) acc[i][j] = (f32x4)(0.f);

    gemm_core(A, Bt, C_, bm, bn, As, Bs, acc, 1);

#pragma unroll
    for (int i = 0; i < 4; ++i)
#pragma unroll
        for (int r = 0; r < 4; ++r) {
            int m = bm + wr * 64 + i * 16 + lg * 4 + r;
#pragma unroll
            for (int j = 0; j < 4; ++j) {
                int n = bn + wc * 64 + j * 16 + lr;
                out[(size_t)m * C_ + n] = acc[i][j][r] + bias[n];
            }
        }
}

// ------------------------- flash attention ---------------------------------
// Grid (64 heads, 32 qtiles): linear id = head + 64*y, so id%8 = head%8 ->
// every XCD sees all q-tile lengths (R9/R11 had all same-length blocks on one
// XCD). qt = 31 - y dispatches heaviest blocks first. Deferred l-sum: per-lane
// partials, one 16-lane reduce in epilogue. exp2f (q pre-scaled by log2e).
#define KPAD 72
#define PPAD 68
#define NT_ (T_ / 64)   // 32 q-tiles
__global__ __launch_bounds__(256) void attn_mfma(
    const ushort* __restrict__ q, const ushort* __restrict__ k,
    const ushort* __restrict__ vt, ushort* __restrict__ o)  // bf16 out
{
    __shared__ ushort Ks[64][KPAD];
    __shared__ ushort Vs[64][KPAD];
    __shared__ ushort Ps[4][16][PPAD];
    const int tid = threadIdx.x;
    const int wid = tid >> 6, lane = tid & 63;
    const int bh = blockIdx.x;                  // head-major: balances XCDs
    const int qt = NT_ - 1 - (int)blockIdx.y;   // heaviest first
    const int q0 = qt * 64;
    const int qw = q0 + wid * 16;
    const int lr = lane & 15, lg = lane >> 4;
    const ushort* qb = q + (size_t)bh * T_ * D_;
    const ushort* kb = k + (size_t)bh * T_ * D_;
    const ushort* vb = vt + (size_t)bh * D_ * T_;

    bf16x8 qf[2];
    qf[0] = *reinterpret_cast<const bf16x8*>(&qb[(size_t)(qw + lr) * D_ + lg * 8]);
    qf[1] = *reinterpret_cast<const bf16x8*>(&qb[(size_t)(qw + lr) * D_ + 32 + lg * 8]);

    f32x4 acc[4];
#pragma unroll
    for (int i = 0; i < 4; ++i) acc[i] = (f32x4)(0.f);
    float m[4], lp[4];
#pragma unroll
    for (int r = 0; r < 4; ++r) { m[r] = -INFINITY; lp[r] = 0.f; }

    const int ntiles = qt + 1;
    for (int t = 0; t < ntiles; ++t) {
        const int kv0 = t * 64;
        __syncthreads();
#pragma unroll
        for (int i = 0; i < 2; ++i) {
            int c = tid + 256 * i;
            int row = c >> 3, col = (c & 7) * 8;
            *reinterpret_cast<bf16x8*>(&Ks[row][col]) =
                *reinterpret_cast<const bf16x8*>(&kb[(size_t)(kv0 + row) * D_ + col]);
        }
#pragma unroll
        for (int i = 0; i < 2; ++i) {
            int c = tid + 256 * i;
            int d = c >> 3, col = (c & 7) * 8;
            *reinterpret_cast<bf16x8*>(&Vs[d][col]) =
                *reinterpret_cast<const bf16x8*>(&vb[(size_t)d * T_ + kv0 + col]);
        }
        __syncthreads();

        f32x4 sv[4];
#pragma unroll
        for (int sub = 0; sub < 4; ++sub) {
            f32x4 c = (f32x4)(0.f);
            bf16x8 b0 = *reinterpret_cast<const bf16x8*>(&Ks[sub * 16 + lr][lg * 8]);
            bf16x8 b1 = *reinterpret_cast<const bf16x8*>(&Ks[sub * 16 + lr][32 + lg * 8]);
            c = __builtin_amdgcn_mfma_f32_16x16x32_bf16(qf[0], b0, c, 0, 0, 0);
            c = __builtin_amdgcn_mfma_f32_16x16x32_bf16(qf[1], b1, c, 0, 0, 0);
            sv[sub] = c;
        }
        if (t == ntiles - 1) {
#pragma unroll
            for (int sub = 0; sub < 4; ++sub)
#pragma unroll
                for (int r = 0; r < 4; ++r)
                    if (sub * 16 + lr > wid * 16 + lg * 4 + r) sv[sub][r] = -INFINITY;
        }
        float rescale[4];
#pragma unroll
        for (int r = 0; r < 4; ++r) {
            float v0 = fmaxf(fmaxf(sv[0][r], sv[1][r]), fmaxf(sv[2][r], sv[3][r]));
            v0 = fmaxf(v0, __shfl_xor(v0, 1));
            v0 = fmaxf(v0, __shfl_xor(v0, 2));
            v0 = fmaxf(v0, __shfl_xor(v0, 4));
            v0 = fmaxf(v0, __shfl_xor(v0, 8));
            float mn = fmaxf(m[r], v0);
            rescale[r] = exp2f(m[r] - mn);   // 0 when m was -inf
            m[r] = mn;
        }
#pragma unroll
        for (int ds = 0; ds < 4; ++ds)
#pragma unroll
            for (int r = 0; r < 4; ++r) acc[ds][r] *= rescale[r];
#pragma unroll
        for (int sub = 0; sub < 4; ++sub)
#pragma unroll
            for (int r = 0; r < 4; ++r)
                sv[sub][r] = exp2f(sv[sub][r] - m[r]);  // exp2(-inf)=0 covers mask
        // deferred l: per-lane partial only (16-lane reduce once, in epilogue)
#pragma unroll
        for (int r = 0; r < 4; ++r)
            lp[r] = lp[r] * rescale[r] + (sv[0][r] + sv[1][r] + sv[2][r] + sv[3][r]);
#pragma unroll
        for (int sub = 0; sub < 4; ++sub)
#pragma unroll
            for (int r = 0; r < 4; ++r)
                Ps[wid][lg * 4 + r][sub * 16 + lr] = f2bf(sv[sub][r]);
#pragma unroll
        for (int kc = 0; kc < 2; ++kc) {
            bf16x8 pa = *reinterpret_cast<const bf16x8*>(&Ps[wid][lr][kc * 32 + lg * 8]);
#pragma unroll
            for (int ds = 0; ds < 4; ++ds) {
                bf16x8 vv = *reinterpret_cast<const bf16x8*>(&Vs[ds * 16 + lr][kc * 32 + lg * 8]);
                acc[ds] = __builtin_amdgcn_mfma_f32_16x16x32_bf16(pa, vv, acc[ds], 0, 0, 0);
            }
        }
    }
    ushort* ob = o + (size_t)bh * T_ * D_;
#pragma unroll
    for (int r = 0; r < 4; ++r) {
        float l = lp[r];
        l += __shfl_xor(l, 1);
        l += __shfl_xor(l, 2);
        l += __shfl_xor(l, 4);
        l += __shfl_xor(l, 8);
        float inv = 1.f / l;
        int row = qw + lg * 4 + r;
#pragma unroll
        for (int ds = 0; ds < 4; ++ds)
            ob[(size_t)row * D_ + ds * 16 + lr] = f2bf(acc[ds][r] * inv);
    }
}

// ---------------------------------------------------------------------------
extern "C" void kernel_launch(void* const* d_in, const int* in_sizes, int n_in,
                              void* d_out, int out_size, void* d_ws, size_t ws_size,
                              hipStream_t stream) {
    const float* x     = (const float*)d_in[0];
    const float* w_qkv = (const float*)d_in[1];
    const float* b_qkv = (const float*)d_in[2];
    const float* w_out = (const float*)d_in[3];
    const float* b_out = (const float*)d_in[4];
    float* out = (float*)d_out;

    const size_t per = (size_t)B_ * H_ * T_ * D_;  // 8M
    ushort* qws   = (ushort*)d_ws;          // 16MB
    ushort* kws   = qws + per;              // 16MB
    ushort* vtws  = kws + per;              // 16MB
    ushort* ows   = vtws + per;             // attn out bf16, 16MB
    ushort* xbf   = ows + per;              // x bf16, 16MB
    ushort* wqkvT = xbf + per;              // 3072*1024 bf16, 6MB
    ushort* woutT = wqkvT + (size_t)3 * C_ * C_; // 1024*1024 bf16, 2MB

    convert_x<<<(B_ * T_ * C_ / 8 + 255) / 256, 256, 0, stream>>>(x, xbf, B_ * T_ * C_ / 8);
    transpose_w<<<dim3(3 * C_ / 32, C_ / 32), 256, 0, stream>>>(w_qkv, wqkvT, C_, 3 * C_);
    transpose_w<<<dim3(C_ / 32, C_ / 32), 256, 0, stream>>>(w_out, woutT, C_, C_);

    dim3 g1(3 * C_ / 128, (B_ * T_) / 128);
    gemm1_mfma<<<g1, 256, 0, stream>>>(xbf, wqkvT, b_qkv, qws, kws, vtws);

    dim3 ga(B_ * H_, NT_);  // (64 heads, 32 qtiles): XCD-balanced, heavy-first
    attn_mfma<<<ga, 256, 0, stream>>>(qws, kws, vtws, ows);

    dim3 g2(C_ / 128, (B_ * T_) / 128);
    gemm2_mfma<<<g2, 256, 0, stream>>>(ows, woutT, b_out, out);
}